// Round 10
// baseline (965.104 us; speedup 1.0000x reference)
//
#include <hip/hip_runtime.h>

// ---------------------------------------------------------------------------
// EnhancedSeparateDomainModel — Round 10: LDS-conflict pad fix + B prefetch
// pipeline + conv1 sliding window.
// R9 model: conv2 LDS-bound (ds_read 1728cyc + conflicts 745cyc vs MFMA
// 1400cyc per block) + exposed B-frag L2 latency under unroll(1).
// Fixes: (1) xls pad 40->36 ushorts (stride 18 banks, gcd(18,32)=2 -> 2-way
// = free per m136); (2) software-pipelined B-frag loads (bcur/bnxt rotation,
// kk=0 loads issued before staging); (3) conv1 register sliding window
// (72 -> 30 LDS reads/thread).
// Attention simplification (S=1): rope(pos=0)=id, softmax(1x1)=1 ->
//   attn(x) = (x @ wv.T) @ wow.T + wob.
// ---------------------------------------------------------------------------

typedef short bf16x8 __attribute__((ext_vector_type(8)));
typedef float f32x4 __attribute__((ext_vector_type(4)));

__device__ __forceinline__ unsigned short bf16_rne(float f) {
    unsigned int u = __float_as_uint(f);
    u += 0x7fffu + ((u >> 16) & 1u);
    return (unsigned short)(u >> 16);
}
__device__ __forceinline__ float bf2f(unsigned short h) {
    unsigned int u = ((unsigned int)h) << 16;
    return __uint_as_float(u);
}

// -------- weight pre-convert: fp32 OIHW -> bf16 [cc][kk][co][ci32] ---------
template <int CIN, int COUT>
__global__ void wcvt_kernel(const float* __restrict__ w, unsigned short* __restrict__ wq) {
    int idx = blockIdx.x * 256 + threadIdx.x;
    if (idx >= COUT * CIN * 9) return;
    int ci = idx & 31;
    int co = (idx >> 5) % COUT;
    int r  = (idx >> 5) / COUT;
    int kk = r % 9;
    int cc = r / 9;
    wq[idx] = bf16_rne(w[((size_t)co * CIN + cc * 32 + ci) * 9 + kk]);
}

// ---------------- conv1: 1->32, 256x256, SAME, relu, NHWC bf16 out --------
// Thread (co, lx): outputs x = 8*lx + s, s=0..7, via 10-float register
// sliding window (30 LDS reads instead of 72).
__global__ void conv1_nhwc_kernel(const float* __restrict__ in, const float* __restrict__ w,
                                  const float* __restrict__ bias, unsigned short* __restrict__ out) {
    __shared__ float xr[3][72];
    __shared__ float ws[288];
    __shared__ float bs[32];
    int x0  = blockIdx.x * 64;
    int y   = blockIdx.y;
    int img = blockIdx.z;
    int tid = threadIdx.x;
    for (int idx = tid; idx < 288; idx += 256) ws[idx] = w[idx];
    if (tid < 32) bs[tid] = bias[tid];
    for (int idx = tid; idx < 3 * 66; idx += 256) {
        int r = idx / 66, c = idx % 66;
        int gy = y - 1 + r, gx = x0 - 1 + c;
        xr[r][c] = (gy >= 0 && gy < 256 && gx >= 0 && gx < 256)
                       ? in[(size_t)img * 65536 + gy * 256 + gx] : 0.f;
    }
    __syncthreads();
    int co = tid & 31, lx = tid >> 5;
    float wk[9];
    #pragma unroll
    for (int k = 0; k < 9; ++k) wk[k] = ws[co * 9 + k];
    float bb = bs[co];
    float xw[3][10];
    #pragma unroll
    for (int r = 0; r < 3; ++r) {
        #pragma unroll
        for (int j = 0; j < 10; ++j) xw[r][j] = xr[r][8 * lx + j];
    }
    unsigned short* op = out + (((size_t)img * 256 + y) * 256 + x0 + 8 * lx) * 32 + co;
    #pragma unroll
    for (int s = 0; s < 8; ++s) {
        float acc = bb;
        #pragma unroll
        for (int ky = 0; ky < 3; ++ky) {
            #pragma unroll
            for (int kx = 0; kx < 3; ++kx) acc = fmaf(wk[ky * 3 + kx], xw[ky][s + kx], acc);
        }
        op[(size_t)s * 32] = bf16_rne(fmaxf(acc, 0.f));
    }
}

// ---------------- MFMA implicit-GEMM 3x3 conv (NHWC bf16) -----------------
// Block: 32x (2 M-frags) x 8y (4 waves x 2 rows) x COUT (NF=COUT/16 N-frags).
// Input staged in LDS (x-stride 36 ushorts: 2-way banks = free); weights
// loaded per-wave from wq [cc][kk][co][ci], software-pipelined (bcur/bnxt).
// D layout (m89/m91): col=lane&15=co, row=4*(lane>>4)+reg=pixel.
template <int CIN, int COUT, int H, bool POOL, int MINW>
__global__ __launch_bounds__(256, MINW) void convmfma_kernel(const unsigned short* __restrict__ in,
                                                             const unsigned short* __restrict__ wq,
                                                             const float* __restrict__ bias,
                                                             unsigned short* __restrict__ out) {
    constexpr int NF = COUT / 16;
    __shared__ __align__(16) unsigned short xls[10][34][36];
    int x0  = blockIdx.x * 32;
    int y0  = blockIdx.y * 8;
    int img = blockIdx.z;
    int tid  = threadIdx.x;
    int lane = tid & 63, wvi = tid >> 6;
    int l15 = lane & 15, q8 = (lane >> 4) << 3;

    f32x4 acc[2][2][NF]; // [yr][mf][nf]
    #pragma unroll
    for (int a = 0; a < 2; ++a)
        #pragma unroll
        for (int b = 0; b < 2; ++b)
            #pragma unroll
            for (int c = 0; c < NF; ++c) acc[a][b][c] = (f32x4){0.f, 0.f, 0.f, 0.f};

    const unsigned short* inI = in + (size_t)img * H * H * CIN;
    bf16x8 bcur[NF], bnxt[NF];

    for (int cc = 0; cc < CIN / 32; ++cc) {
        if (cc) __syncthreads();
        const unsigned short* wqc = wq + (size_t)cc * 9 * COUT * 32;
        // prefetch B-frags for kk=0 — overlaps with the staging below
        #pragma unroll
        for (int nf = 0; nf < NF; ++nf)
            bcur[nf] = *(const bf16x8*)&wqc[((size_t)(nf * 16 + l15)) * 32 + q8];
        // stage input chunk: rows y0-1..y0+8, cols x0-1..x0+32, ci cc*32..+31
        for (int idx = tid; idx < 10 * 34 * 4; idx += 256) {
            int row = idx / 136, rem = idx % 136, xx = rem >> 2, c4 = rem & 3;
            int gy = y0 - 1 + row, gx = x0 - 1 + xx;
            uint4 v = {0u, 0u, 0u, 0u};
            if (gy >= 0 && gy < H && gx >= 0 && gx < H)
                v = *(const uint4*)&inI[((size_t)gy * H + gx) * CIN + cc * 32 + c4 * 8];
            *(uint4*)&xls[row][xx][c4 * 8] = v;
        }
        __syncthreads();

        #pragma unroll 1
        for (int kk = 0; kk < 9; ++kk) {
            int ky = kk / 3, kx = kk - ky * 3;
            int kn = (kk < 8) ? kk + 1 : 8; // clamped prefetch index
            #pragma unroll
            for (int nf = 0; nf < NF; ++nf)
                bnxt[nf] = *(const bf16x8*)&wqc[((size_t)kn * COUT + nf * 16 + l15) * 32 + q8];
            #pragma unroll
            for (int yr = 0; yr < 2; ++yr) {
                int row = 2 * wvi + yr + ky;
                #pragma unroll
                for (int mf = 0; mf < 2; ++mf) {
                    bf16x8 a = *(const bf16x8*)&xls[row][mf * 16 + l15 + kx][q8];
                    #pragma unroll
                    for (int nf = 0; nf < NF; ++nf)
                        acc[yr][mf][nf] =
                            __builtin_amdgcn_mfma_f32_16x16x32_bf16(a, bcur[nf], acc[yr][mf][nf], 0, 0, 0);
                }
            }
            #pragma unroll
            for (int nf = 0; nf < NF; ++nf) bcur[nf] = bnxt[nf];
        }
    }

    float bv[NF];
    #pragma unroll
    for (int nf = 0; nf < NF; ++nf) bv[nf] = bias[nf * 16 + l15];

    if constexpr (POOL) {
        constexpr int Wp = H / 2;
        int yp = y0 / 2 + wvi;
        #pragma unroll
        for (int nf = 0; nf < NF; ++nf) {
            int co = nf * 16 + l15;
            #pragma unroll
            for (int mf = 0; mf < 2; ++mf) {
                #pragma unroll
                for (int t = 0; t < 2; ++t) {
                    float m = fmaxf(fmaxf(acc[0][mf][nf][2 * t], acc[0][mf][nf][2 * t + 1]),
                                    fmaxf(acc[1][mf][nf][2 * t], acc[1][mf][nf][2 * t + 1]));
                    m = fmaxf(m + bv[nf], 0.f);
                    int xp = x0 / 2 + mf * 8 + 2 * (lane >> 4) + t;
                    out[(((size_t)img * Wp + yp) * Wp + xp) * COUT + co] = bf16_rne(m);
                }
            }
        }
    } else {
        #pragma unroll
        for (int yr = 0; yr < 2; ++yr) {
            int y = y0 + 2 * wvi + yr;
            #pragma unroll
            for (int mf = 0; mf < 2; ++mf) {
                #pragma unroll
                for (int nf = 0; nf < NF; ++nf) {
                    int co = nf * 16 + l15;
                    #pragma unroll
                    for (int r = 0; r < 4; ++r) {
                        int x = x0 + mf * 16 + 4 * (lane >> 4) + r;
                        out[(((size_t)img * H + y) * H + x) * COUT + co] =
                            bf16_rne(fmaxf(acc[yr][mf][nf][r] + bv[nf], 0.f));
                    }
                }
            }
        }
    }
}

// ---------------- adaptive avg-pool (NHWC 64x64x64 -> 4x4) + FC -----------
__global__ void avgfc_kernel(const unsigned short* __restrict__ pin, const float* __restrict__ fcw,
                             const float* __restrict__ fcb, float* __restrict__ tf) {
    __shared__ float av[1024];
    int b = blockIdx.x, tid = threadIdx.x;
    const unsigned short* p = pin + (size_t)b * 64 * 64 * 64;
    for (int idx = tid; idx < 1024; idx += 256) {
        int c = idx & 63, pq = idx >> 6, i = pq >> 2, j = pq & 3;
        float s = 0.f;
        for (int r = 0; r < 16; ++r)
            for (int cc2 = 0; cc2 < 16; ++cc2)
                s += bf2f(p[(((size_t)(i * 16 + r) * 64) + (j * 16 + cc2)) * 64 + c]);
        av[c * 16 + pq] = s * (1.f / 256.f);
    }
    __syncthreads();
    if (tid < 128) {
        float s         = fcb[tid];
        const float* wr = fcw + (size_t)tid * 1024;
        for (int i = 0; i < 1024; ++i) s = fmaf(av[i], wr[i], s);
        tf[b * 128 + tid] = s;
    }
}

// ---------------- patch embed (fp32, reads original input) ----------------
__global__ void patch_kernel(const float* __restrict__ sig, const float* __restrict__ pew,
                             const float* __restrict__ peb, float* __restrict__ tp) {
    __shared__ float ps[16][168];
    __shared__ float partial[4][64];
    int b   = blockIdx.x;
    int tid = threadIdx.x;
    for (int idx = tid; idx < 16 * 168; idx += 256) {
        int r = idx / 168, c = idx % 168;
        ps[r][c] = sig[(size_t)b * 65536 + r * 256 + c];
    }
    __syncthreads();
    int e = tid & 63, pg = tid >> 6;
    const float* wr = pew + (size_t)e * 256;
    float s = 0.f;
    for (int r = 0; r < 16; ++r) {
        #pragma unroll
        for (int c = 0; c < 16; ++c) {
            float acc = 0.f;
            for (int pi = pg; pi < 20; pi += 4) acc += ps[r][8 * pi + c];
            s = fmaf(acc, wr[r * 16 + c], s);
        }
    }
    partial[pg][e] = s;
    __syncthreads();
    if (tid < 64) {
        tp[b * 64 + tid] =
            (partial[0][tid] + partial[1][tid] + partial[2][tid] + partial[3][tid]) * (1.f / 20.f) +
            peb[tid];
    }
}

// ---------------- reduce (128->64, relu) + simplified attention -----------
__global__ void redattn_kernel(const float* __restrict__ tf, const float* __restrict__ redw,
                               const float* __restrict__ redb, const float* __restrict__ wv,
                               const float* __restrict__ wow, const float* __restrict__ wob,
                               float* __restrict__ ta) {
    __shared__ float stf[128], str_[64], sv[64];
    int b = blockIdx.x, t = threadIdx.x; // 64 threads
    stf[t]      = tf[b * 128 + t];
    stf[t + 64] = tf[b * 128 + 64 + t];
    __syncthreads();
    float s = redb[t];
    for (int i = 0; i < 128; ++i) s = fmaf(stf[i], redw[t * 128 + i], s);
    str_[t] = fmaxf(s, 0.f);
    __syncthreads();
    s = 0.f;
    for (int i = 0; i < 64; ++i) s = fmaf(str_[i], wv[t * 64 + i], s);
    sv[t] = s;
    __syncthreads();
    s = wob[t];
    for (int i = 0; i < 64; ++i) s = fmaf(sv[i], wow[t * 64 + i], s);
    ta[b * 64 + t] = s;
}

// ---------------- classifier head -----------------------------------------
__global__ void head_kernel(const float* __restrict__ taT, const float* __restrict__ taF,
                            const float* __restrict__ tpT, const float* __restrict__ tpF,
                            const float* __restrict__ c1w, const float* __restrict__ c1b,
                            const float* __restrict__ c2w, const float* __restrict__ c2b,
                            const float* __restrict__ c3w, const float* __restrict__ c3b,
                            float* __restrict__ outp) {
    __shared__ float f0[256], h1[256], h2[128];
    int b = blockIdx.x, t = threadIdx.x;
    int seg = t >> 6, e = t & 63;
    const float* sp_ = (seg == 0) ? taT : (seg == 1) ? taF : (seg == 2) ? tpT : tpF;
    f0[t] = sp_[b * 64 + e];
    __syncthreads();
    {
        float s = c1b[t];
        for (int i = 0; i < 256; ++i) s = fmaf(f0[i], c1w[t * 256 + i], s);
        h1[t] = fmaxf(s, 0.f);
    }
    __syncthreads();
    if (t < 128) {
        float s = c2b[t];
        for (int i = 0; i < 256; ++i) s = fmaf(h1[i], c2w[t * 256 + i], s);
        h2[t] = fmaxf(s, 0.f);
    }
    __syncthreads();
    if (t < 2) {
        float s = c3b[t];
        for (int i = 0; i < 128; ++i) s = fmaf(h2[i], c3w[t * 128 + i], s);
        outp[b * 2 + t] = s;
    }
}

// ---------------------------------------------------------------------------
extern "C" void kernel_launch(void* const* d_in, const int* in_sizes, int n_in,
                              void* d_out, int out_size, void* d_ws, size_t ws_size,
                              hipStream_t stream) {
    // Per-image bf16 intermediates (ushort counts):
    //   A: conv1 out 256*256*32 = 2,097,152 (conv3 out 128*128*64 aliases)
    //   B: conv2 pooled 128*128*32 = 524,288 (conv4 pooled 64*64*64 aliases)
    constexpr size_t A_PER = 2097152, B_PER = 524288;
    // small vectors (64KB floats) + converted weights (2 branches x 64512 bf16)
    constexpr size_t SMALL_BYTES = 65536 + 262144;

    int CH = 32;
    while (CH > 1 && ((size_t)CH * (A_PER + B_PER) * 2 + SMALL_BYTES) > ws_size) CH >>= 1;
    const int NCHUNK = 32 / CH;

    unsigned short* A  = (unsigned short*)d_ws;
    unsigned short* Bb = A + (size_t)CH * A_PER;
    float* SM = (float*)(Bb + (size_t)CH * B_PER);
    float* tfB[2] = {SM, SM + 4096};
    float* tpB[2] = {SM + 8192, SM + 10240};
    float* taB[2] = {SM + 12288, SM + 14336};
    unsigned short* WQ = (unsigned short*)(SM + 16384);

    for (int br = 0; br < 2; ++br) {
        const float* in   = (const float*)d_in[br];
        const int base    = 2 + br * 19;
        const float* c1w  = (const float*)d_in[base + 0];
        const float* c1b  = (const float*)d_in[base + 1];
        const float* c2w  = (const float*)d_in[base + 2];
        const float* c2b  = (const float*)d_in[base + 3];
        const float* c3w  = (const float*)d_in[base + 4];
        const float* c3b  = (const float*)d_in[base + 5];
        const float* c4w  = (const float*)d_in[base + 6];
        const float* c4b  = (const float*)d_in[base + 7];
        const float* fcw  = (const float*)d_in[base + 8];
        const float* fcb  = (const float*)d_in[base + 9];
        const float* redw = (const float*)d_in[base + 10];
        const float* redb = (const float*)d_in[base + 11];
        const float* wv_  = (const float*)d_in[base + 14];
        const float* wow_ = (const float*)d_in[base + 15];
        const float* wob_ = (const float*)d_in[base + 16];
        const float* pew  = (const float*)d_in[base + 17];
        const float* peb  = (const float*)d_in[base + 18];

        unsigned short* wq2 = WQ + (size_t)br * 64512;
        unsigned short* wq3 = wq2 + 9216;
        unsigned short* wq4 = wq3 + 18432;
        wcvt_kernel<32, 32><<<36, 256, 0, stream>>>(c2w, wq2);
        wcvt_kernel<32, 64><<<72, 256, 0, stream>>>(c3w, wq3);
        wcvt_kernel<64, 64><<<144, 256, 0, stream>>>(c4w, wq4);

        for (int ck = 0; ck < NCHUNK; ++ck) {
            const float* inC = in + (size_t)ck * CH * 65536;
            conv1_nhwc_kernel<<<dim3(4, 256, CH), 256, 0, stream>>>(inC, c1w, c1b, A);
            convmfma_kernel<32, 32, 256, true, 4>
                <<<dim3(8, 32, CH), 256, 0, stream>>>(A, wq2, c2b, Bb);
            convmfma_kernel<32, 64, 128, false, 3>
                <<<dim3(4, 16, CH), 256, 0, stream>>>(Bb, wq3, c3b, A);
            convmfma_kernel<64, 64, 128, true, 3>
                <<<dim3(4, 16, CH), 256, 0, stream>>>(A, wq4, c4b, Bb);
            avgfc_kernel<<<CH, 256, 0, stream>>>(Bb, fcw, fcb, tfB[br] + (size_t)ck * CH * 128);
            patch_kernel<<<CH, 256, 0, stream>>>(inC, pew, peb, tpB[br] + (size_t)ck * CH * 64);
        }
        redattn_kernel<<<32, 64, 0, stream>>>(tfB[br], redw, redb, wv_, wow_, wob_, taB[br]);
    }

    head_kernel<<<32, 256, 0, stream>>>(taB[0], taB[1], tpB[0], tpB[1],
                                        (const float*)d_in[40], (const float*)d_in[41],
                                        (const float*)d_in[42], (const float*)d_in[43],
                                        (const float*)d_in[44], (const float*)d_in[45],
                                        (float*)d_out);
}

// Round 11
// 769.408 us; speedup vs baseline: 1.2543x; 1.2543x over previous
//
#include <hip/hip_runtime.h>

// ---------------------------------------------------------------------------
// EnhancedSeparateDomainModel — Round 11: revert xls pad 36 -> 40.
// R10 regression diagnosis: pad 36 ushorts = 72B x-stride broke the 16B
// alignment of the uint4 LDS accesses (odd xx -> addr ≡ 8 mod 16), forcing
// the compiler to split ds_*_b128 into b64 pairs -> 2x DS instructions on an
// LDS-bound kernel (dur 2x, MfmaUtil halved, conflicts *down* because b64).
// Pad 40 = 80B keeps every access 16B-aligned and is already minimum-phase
// for b128 (8 lanes/bank). Keep R10's B-prefetch pipeline + conv1 window.
// Attention simplification (S=1): rope(pos=0)=id, softmax(1x1)=1 ->
//   attn(x) = (x @ wv.T) @ wow.T + wob.
// ---------------------------------------------------------------------------

typedef short bf16x8 __attribute__((ext_vector_type(8)));
typedef float f32x4 __attribute__((ext_vector_type(4)));

__device__ __forceinline__ unsigned short bf16_rne(float f) {
    unsigned int u = __float_as_uint(f);
    u += 0x7fffu + ((u >> 16) & 1u);
    return (unsigned short)(u >> 16);
}
__device__ __forceinline__ float bf2f(unsigned short h) {
    unsigned int u = ((unsigned int)h) << 16;
    return __uint_as_float(u);
}

// -------- weight pre-convert: fp32 OIHW -> bf16 [cc][kk][co][ci32] ---------
template <int CIN, int COUT>
__global__ void wcvt_kernel(const float* __restrict__ w, unsigned short* __restrict__ wq) {
    int idx = blockIdx.x * 256 + threadIdx.x;
    if (idx >= COUT * CIN * 9) return;
    int ci = idx & 31;
    int co = (idx >> 5) % COUT;
    int r  = (idx >> 5) / COUT;
    int kk = r % 9;
    int cc = r / 9;
    wq[idx] = bf16_rne(w[((size_t)co * CIN + cc * 32 + ci) * 9 + kk]);
}

// ---------------- conv1: 1->32, 256x256, SAME, relu, NHWC bf16 out --------
// Thread (co, lx): outputs x = 8*lx + s, s=0..7, via 10-float register
// sliding window (30 LDS reads instead of 72).
__global__ void conv1_nhwc_kernel(const float* __restrict__ in, const float* __restrict__ w,
                                  const float* __restrict__ bias, unsigned short* __restrict__ out) {
    __shared__ float xr[3][72];
    __shared__ float ws[288];
    __shared__ float bs[32];
    int x0  = blockIdx.x * 64;
    int y   = blockIdx.y;
    int img = blockIdx.z;
    int tid = threadIdx.x;
    for (int idx = tid; idx < 288; idx += 256) ws[idx] = w[idx];
    if (tid < 32) bs[tid] = bias[tid];
    for (int idx = tid; idx < 3 * 66; idx += 256) {
        int r = idx / 66, c = idx % 66;
        int gy = y - 1 + r, gx = x0 - 1 + c;
        xr[r][c] = (gy >= 0 && gy < 256 && gx >= 0 && gx < 256)
                       ? in[(size_t)img * 65536 + gy * 256 + gx] : 0.f;
    }
    __syncthreads();
    int co = tid & 31, lx = tid >> 5;
    float wk[9];
    #pragma unroll
    for (int k = 0; k < 9; ++k) wk[k] = ws[co * 9 + k];
    float bb = bs[co];
    float xw[3][10];
    #pragma unroll
    for (int r = 0; r < 3; ++r) {
        #pragma unroll
        for (int j = 0; j < 10; ++j) xw[r][j] = xr[r][8 * lx + j];
    }
    unsigned short* op = out + (((size_t)img * 256 + y) * 256 + x0 + 8 * lx) * 32 + co;
    #pragma unroll
    for (int s = 0; s < 8; ++s) {
        float acc = bb;
        #pragma unroll
        for (int ky = 0; ky < 3; ++ky) {
            #pragma unroll
            for (int kx = 0; kx < 3; ++kx) acc = fmaf(wk[ky * 3 + kx], xw[ky][s + kx], acc);
        }
        op[(size_t)s * 32] = bf16_rne(fmaxf(acc, 0.f));
    }
}

// ---------------- MFMA implicit-GEMM 3x3 conv (NHWC bf16) -----------------
// Block: 32x (2 M-frags) x 8y (4 waves x 2 rows) x COUT (NF=COUT/16 N-frags).
// Input staged in LDS (x-stride 40 ushorts = 80B: 16B-aligned, min-phase
// b128); weights loaded per-wave from wq [cc][kk][co][ci], software-
// pipelined (bcur/bnxt rotation; kk=0 loads issued before staging).
// D layout (m89/m91): col=lane&15=co, row=4*(lane>>4)+reg=pixel.
template <int CIN, int COUT, int H, bool POOL, int MINW>
__global__ __launch_bounds__(256, MINW) void convmfma_kernel(const unsigned short* __restrict__ in,
                                                             const unsigned short* __restrict__ wq,
                                                             const float* __restrict__ bias,
                                                             unsigned short* __restrict__ out) {
    constexpr int NF = COUT / 16;
    __shared__ __align__(16) unsigned short xls[10][34][40];
    int x0  = blockIdx.x * 32;
    int y0  = blockIdx.y * 8;
    int img = blockIdx.z;
    int tid  = threadIdx.x;
    int lane = tid & 63, wvi = tid >> 6;
    int l15 = lane & 15, q8 = (lane >> 4) << 3;

    f32x4 acc[2][2][NF]; // [yr][mf][nf]
    #pragma unroll
    for (int a = 0; a < 2; ++a)
        #pragma unroll
        for (int b = 0; b < 2; ++b)
            #pragma unroll
            for (int c = 0; c < NF; ++c) acc[a][b][c] = (f32x4){0.f, 0.f, 0.f, 0.f};

    const unsigned short* inI = in + (size_t)img * H * H * CIN;
    bf16x8 bcur[NF], bnxt[NF];

    for (int cc = 0; cc < CIN / 32; ++cc) {
        if (cc) __syncthreads();
        const unsigned short* wqc = wq + (size_t)cc * 9 * COUT * 32;
        // prefetch B-frags for kk=0 — overlaps with the staging below
        #pragma unroll
        for (int nf = 0; nf < NF; ++nf)
            bcur[nf] = *(const bf16x8*)&wqc[((size_t)(nf * 16 + l15)) * 32 + q8];
        // stage input chunk: rows y0-1..y0+8, cols x0-1..x0+32, ci cc*32..+31
        for (int idx = tid; idx < 10 * 34 * 4; idx += 256) {
            int row = idx / 136, rem = idx % 136, xx = rem >> 2, c4 = rem & 3;
            int gy = y0 - 1 + row, gx = x0 - 1 + xx;
            uint4 v = {0u, 0u, 0u, 0u};
            if (gy >= 0 && gy < H && gx >= 0 && gx < H)
                v = *(const uint4*)&inI[((size_t)gy * H + gx) * CIN + cc * 32 + c4 * 8];
            *(uint4*)&xls[row][xx][c4 * 8] = v;
        }
        __syncthreads();

        #pragma unroll 1
        for (int kk = 0; kk < 9; ++kk) {
            int ky = kk / 3, kx = kk - ky * 3;
            int kn = (kk < 8) ? kk + 1 : 8; // clamped prefetch index
            #pragma unroll
            for (int nf = 0; nf < NF; ++nf)
                bnxt[nf] = *(const bf16x8*)&wqc[((size_t)kn * COUT + nf * 16 + l15) * 32 + q8];
            #pragma unroll
            for (int yr = 0; yr < 2; ++yr) {
                int row = 2 * wvi + yr + ky;
                #pragma unroll
                for (int mf = 0; mf < 2; ++mf) {
                    bf16x8 a = *(const bf16x8*)&xls[row][mf * 16 + l15 + kx][q8];
                    #pragma unroll
                    for (int nf = 0; nf < NF; ++nf)
                        acc[yr][mf][nf] =
                            __builtin_amdgcn_mfma_f32_16x16x32_bf16(a, bcur[nf], acc[yr][mf][nf], 0, 0, 0);
                }
            }
            #pragma unroll
            for (int nf = 0; nf < NF; ++nf) bcur[nf] = bnxt[nf];
        }
    }

    float bv[NF];
    #pragma unroll
    for (int nf = 0; nf < NF; ++nf) bv[nf] = bias[nf * 16 + l15];

    if constexpr (POOL) {
        constexpr int Wp = H / 2;
        int yp = y0 / 2 + wvi;
        #pragma unroll
        for (int nf = 0; nf < NF; ++nf) {
            int co = nf * 16 + l15;
            #pragma unroll
            for (int mf = 0; mf < 2; ++mf) {
                #pragma unroll
                for (int t = 0; t < 2; ++t) {
                    float m = fmaxf(fmaxf(acc[0][mf][nf][2 * t], acc[0][mf][nf][2 * t + 1]),
                                    fmaxf(acc[1][mf][nf][2 * t], acc[1][mf][nf][2 * t + 1]));
                    m = fmaxf(m + bv[nf], 0.f);
                    int xp = x0 / 2 + mf * 8 + 2 * (lane >> 4) + t;
                    out[(((size_t)img * Wp + yp) * Wp + xp) * COUT + co] = bf16_rne(m);
                }
            }
        }
    } else {
        #pragma unroll
        for (int yr = 0; yr < 2; ++yr) {
            int y = y0 + 2 * wvi + yr;
            #pragma unroll
            for (int mf = 0; mf < 2; ++mf) {
                #pragma unroll
                for (int nf = 0; nf < NF; ++nf) {
                    int co = nf * 16 + l15;
                    #pragma unroll
                    for (int r = 0; r < 4; ++r) {
                        int x = x0 + mf * 16 + 4 * (lane >> 4) + r;
                        out[(((size_t)img * H + y) * H + x) * COUT + co] =
                            bf16_rne(fmaxf(acc[yr][mf][nf][r] + bv[nf], 0.f));
                    }
                }
            }
        }
    }
}

// ---------------- adaptive avg-pool (NHWC 64x64x64 -> 4x4) + FC -----------
__global__ void avgfc_kernel(const unsigned short* __restrict__ pin, const float* __restrict__ fcw,
                             const float* __restrict__ fcb, float* __restrict__ tf) {
    __shared__ float av[1024];
    int b = blockIdx.x, tid = threadIdx.x;
    const unsigned short* p = pin + (size_t)b * 64 * 64 * 64;
    for (int idx = tid; idx < 1024; idx += 256) {
        int c = idx & 63, pq = idx >> 6, i = pq >> 2, j = pq & 3;
        float s = 0.f;
        for (int r = 0; r < 16; ++r)
            for (int cc2 = 0; cc2 < 16; ++cc2)
                s += bf2f(p[(((size_t)(i * 16 + r) * 64) + (j * 16 + cc2)) * 64 + c]);
        av[c * 16 + pq] = s * (1.f / 256.f);
    }
    __syncthreads();
    if (tid < 128) {
        float s         = fcb[tid];
        const float* wr = fcw + (size_t)tid * 1024;
        for (int i = 0; i < 1024; ++i) s = fmaf(av[i], wr[i], s);
        tf[b * 128 + tid] = s;
    }
}

// ---------------- patch embed (fp32, reads original input) ----------------
__global__ void patch_kernel(const float* __restrict__ sig, const float* __restrict__ pew,
                             const float* __restrict__ peb, float* __restrict__ tp) {
    __shared__ float ps[16][168];
    __shared__ float partial[4][64];
    int b   = blockIdx.x;
    int tid = threadIdx.x;
    for (int idx = tid; idx < 16 * 168; idx += 256) {
        int r = idx / 168, c = idx % 168;
        ps[r][c] = sig[(size_t)b * 65536 + r * 256 + c];
    }
    __syncthreads();
    int e = tid & 63, pg = tid >> 6;
    const float* wr = pew + (size_t)e * 256;
    float s = 0.f;
    for (int r = 0; r < 16; ++r) {
        #pragma unroll
        for (int c = 0; c < 16; ++c) {
            float acc = 0.f;
            for (int pi = pg; pi < 20; pi += 4) acc += ps[r][8 * pi + c];
            s = fmaf(acc, wr[r * 16 + c], s);
        }
    }
    partial[pg][e] = s;
    __syncthreads();
    if (tid < 64) {
        tp[b * 64 + tid] =
            (partial[0][tid] + partial[1][tid] + partial[2][tid] + partial[3][tid]) * (1.f / 20.f) +
            peb[tid];
    }
}

// ---------------- reduce (128->64, relu) + simplified attention -----------
__global__ void redattn_kernel(const float* __restrict__ tf, const float* __restrict__ redw,
                               const float* __restrict__ redb, const float* __restrict__ wv,
                               const float* __restrict__ wow, const float* __restrict__ wob,
                               float* __restrict__ ta) {
    __shared__ float stf[128], str_[64], sv[64];
    int b = blockIdx.x, t = threadIdx.x; // 64 threads
    stf[t]      = tf[b * 128 + t];
    stf[t + 64] = tf[b * 128 + 64 + t];
    __syncthreads();
    float s = redb[t];
    for (int i = 0; i < 128; ++i) s = fmaf(stf[i], redw[t * 128 + i], s);
    str_[t] = fmaxf(s, 0.f);
    __syncthreads();
    s = 0.f;
    for (int i = 0; i < 64; ++i) s = fmaf(str_[i], wv[t * 64 + i], s);
    sv[t] = s;
    __syncthreads();
    s = wob[t];
    for (int i = 0; i < 64; ++i) s = fmaf(sv[i], wow[t * 64 + i], s);
    ta[b * 64 + t] = s;
}

// ---------------- classifier head -----------------------------------------
__global__ void head_kernel(const float* __restrict__ taT, const float* __restrict__ taF,
                            const float* __restrict__ tpT, const float* __restrict__ tpF,
                            const float* __restrict__ c1w, const float* __restrict__ c1b,
                            const float* __restrict__ c2w, const float* __restrict__ c2b,
                            const float* __restrict__ c3w, const float* __restrict__ c3b,
                            float* __restrict__ outp) {
    __shared__ float f0[256], h1[256], h2[128];
    int b = blockIdx.x, t = threadIdx.x;
    int seg = t >> 6, e = t & 63;
    const float* sp_ = (seg == 0) ? taT : (seg == 1) ? taF : (seg == 2) ? tpT : tpF;
    f0[t] = sp_[b * 64 + e];
    __syncthreads();
    {
        float s = c1b[t];
        for (int i = 0; i < 256; ++i) s = fmaf(f0[i], c1w[t * 256 + i], s);
        h1[t] = fmaxf(s, 0.f);
    }
    __syncthreads();
    if (t < 128) {
        float s = c2b[t];
        for (int i = 0; i < 256; ++i) s = fmaf(h1[i], c2w[t * 256 + i], s);
        h2[t] = fmaxf(s, 0.f);
    }
    __syncthreads();
    if (t < 2) {
        float s = c3b[t];
        for (int i = 0; i < 128; ++i) s = fmaf(h2[i], c3w[t * 128 + i], s);
        outp[b * 2 + t] = s;
    }
}

// ---------------------------------------------------------------------------
extern "C" void kernel_launch(void* const* d_in, const int* in_sizes, int n_in,
                              void* d_out, int out_size, void* d_ws, size_t ws_size,
                              hipStream_t stream) {
    // Per-image bf16 intermediates (ushort counts):
    //   A: conv1 out 256*256*32 = 2,097,152 (conv3 out 128*128*64 aliases)
    //   B: conv2 pooled 128*128*32 = 524,288 (conv4 pooled 64*64*64 aliases)
    constexpr size_t A_PER = 2097152, B_PER = 524288;
    // small vectors (64KB floats) + converted weights (2 branches x 64512 bf16)
    constexpr size_t SMALL_BYTES = 65536 + 262144;

    int CH = 32;
    while (CH > 1 && ((size_t)CH * (A_PER + B_PER) * 2 + SMALL_BYTES) > ws_size) CH >>= 1;
    const int NCHUNK = 32 / CH;

    unsigned short* A  = (unsigned short*)d_ws;
    unsigned short* Bb = A + (size_t)CH * A_PER;
    float* SM = (float*)(Bb + (size_t)CH * B_PER);
    float* tfB[2] = {SM, SM + 4096};
    float* tpB[2] = {SM + 8192, SM + 10240};
    float* taB[2] = {SM + 12288, SM + 14336};
    unsigned short* WQ = (unsigned short*)(SM + 16384);

    for (int br = 0; br < 2; ++br) {
        const float* in   = (const float*)d_in[br];
        const int base    = 2 + br * 19;
        const float* c1w  = (const float*)d_in[base + 0];
        const float* c1b  = (const float*)d_in[base + 1];
        const float* c2w  = (const float*)d_in[base + 2];
        const float* c2b  = (const float*)d_in[base + 3];
        const float* c3w  = (const float*)d_in[base + 4];
        const float* c3b  = (const float*)d_in[base + 5];
        const float* c4w  = (const float*)d_in[base + 6];
        const float* c4b  = (const float*)d_in[base + 7];
        const float* fcw  = (const float*)d_in[base + 8];
        const float* fcb  = (const float*)d_in[base + 9];
        const float* redw = (const float*)d_in[base + 10];
        const float* redb = (const float*)d_in[base + 11];
        const float* wv_  = (const float*)d_in[base + 14];
        const float* wow_ = (const float*)d_in[base + 15];
        const float* wob_ = (const float*)d_in[base + 16];
        const float* pew  = (const float*)d_in[base + 17];
        const float* peb  = (const float*)d_in[base + 18];

        unsigned short* wq2 = WQ + (size_t)br * 64512;
        unsigned short* wq3 = wq2 + 9216;
        unsigned short* wq4 = wq3 + 18432;
        wcvt_kernel<32, 32><<<36, 256, 0, stream>>>(c2w, wq2);
        wcvt_kernel<32, 64><<<72, 256, 0, stream>>>(c3w, wq3);
        wcvt_kernel<64, 64><<<144, 256, 0, stream>>>(c4w, wq4);

        for (int ck = 0; ck < NCHUNK; ++ck) {
            const float* inC = in + (size_t)ck * CH * 65536;
            conv1_nhwc_kernel<<<dim3(4, 256, CH), 256, 0, stream>>>(inC, c1w, c1b, A);
            convmfma_kernel<32, 32, 256, true, 4>
                <<<dim3(8, 32, CH), 256, 0, stream>>>(A, wq2, c2b, Bb);
            convmfma_kernel<32, 64, 128, false, 3>
                <<<dim3(4, 16, CH), 256, 0, stream>>>(Bb, wq3, c3b, A);
            convmfma_kernel<64, 64, 128, true, 3>
                <<<dim3(4, 16, CH), 256, 0, stream>>>(A, wq4, c4b, Bb);
            avgfc_kernel<<<CH, 256, 0, stream>>>(Bb, fcw, fcb, tfB[br] + (size_t)ck * CH * 128);
            patch_kernel<<<CH, 256, 0, stream>>>(inC, pew, peb, tpB[br] + (size_t)ck * CH * 64);
        }
        redattn_kernel<<<32, 64, 0, stream>>>(tfB[br], redw, redb, wv_, wow_, wob_, taB[br]);
    }

    head_kernel<<<32, 256, 0, stream>>>(taB[0], taB[1], tpB[0], tpB[1],
                                        (const float*)d_in[40], (const float*)d_in[41],
                                        (const float*)d_in[42], (const float*)d_in[43],
                                        (const float*)d_in[44], (const float*)d_in[45],
                                        (float*)d_out);
}